// Round 7
// baseline (739.660 us; speedup 1.0000x reference)
//
#include <hip/hip_runtime.h>

#define NN 100000
#define NE 1200000
#define NG 2048
#define VOCAB 10000
#define D 64
#define C 2

#define SB 512
#define NB ((NN + SB - 1) / SB)   // 196 scan blocks

__device__ __forceinline__ int atomAddI(int* p, int v) {
    return __hip_atomic_fetch_add(p, v, __ATOMIC_RELAXED, __HIP_MEMORY_SCOPE_AGENT);
}
__device__ __forceinline__ void atomAddF(float* p, float v) {
    __hip_atomic_fetch_add(p, v, __ATOMIC_RELAXED, __HIP_MEMORY_SCOPE_AGENT);
}

// ---------------- CSR build ----------------
__global__ void __launch_bounds__(256) k_hist(const int* __restrict__ dst, int* __restrict__ deg) {
    int e = blockIdx.x * blockDim.x + threadIdx.x;
    if (e < NE) atomAddI(&deg[dst[e]], 1);
}

__global__ void __launch_bounds__(256) k_scan1(const int* __restrict__ deg, int* __restrict__ locx,
                        int* __restrict__ bsum) {
    __shared__ int sm[256];
    int t = threadIdx.x;
    int i0 = blockIdx.x * SB + 2 * t;
    int d0 = (i0 < NN) ? deg[i0] : 0;
    int d1 = (i0 + 1 < NN) ? deg[i0 + 1] : 0;
    int s = d0 + d1;
    sm[t] = s;
    __syncthreads();
    for (int off = 1; off < 256; off <<= 1) {
        int v = (t >= off) ? sm[t - off] : 0;
        __syncthreads();
        sm[t] += v;
        __syncthreads();
    }
    int ex = sm[t] - s;
    if (i0 < NN) locx[i0] = ex;
    if (i0 + 1 < NN) locx[i0 + 1] = ex + d0;
    if (t == 255) bsum[blockIdx.x] = sm[255];
}

__global__ void __launch_bounds__(256) k_scan2(const int* __restrict__ bsum, int* __restrict__ boff) {
    __shared__ int sm[NB];
    int t = threadIdx.x;
    if (t < NB) sm[t] = bsum[t];
    __syncthreads();
    if (t == 0) {
        int run = 0;
        for (int i = 0; i < NB; ++i) { int v = sm[i]; sm[i] = run; run += v; }
    }
    __syncthreads();
    if (t < NB) boff[t] = sm[t];
}

__global__ void __launch_bounds__(512) k_scan3(const int* __restrict__ locx, const int* __restrict__ boff,
                        int* __restrict__ start, int* __restrict__ cursor) {
    int i = blockIdx.x * SB + threadIdx.x;
    if (i < NN) {
        int v = locx[i] + boff[blockIdx.x];
        start[i] = v;
        cursor[i] = v;
    }
    if (i == 0) start[NN] = NE;
}

__global__ void __launch_bounds__(256) k_build(const int* __restrict__ src, const int* __restrict__ dst,
                        int* __restrict__ cursor, int* __restrict__ csr_src) {
    int e = blockIdx.x * blockDim.x + threadIdx.x;
    if (e < NE) {
        int pos = atomAddI(&cursor[dst[e]], 1);
        csr_src[pos] = src[e];
    }
}

// ---------------- chunked CSR aggregate, chunk-per-XCD, float2 lanes ----------------
// FIRST: gather emb[x[csr[e]]] directly (no materialized h0). Else gather slab gT.
// lane = es(16 edges) x f2(4 float2) -> 16 edges per load instr; unroll 2x16 so
// 4+ loads are in flight; guards applied to the VALUE (cndmask), indices clamp to 0.
template<bool FIRST>
__global__ void __launch_bounds__(256) k_agg(const int* __restrict__ start,
        const int* __restrict__ csr, const int* __restrict__ x,
        const float* __restrict__ emb, const float* __restrict__ gT,
        float* __restrict__ aggT) {
    int lane = threadIdx.x & 63;
    int wave = threadIdx.x >> 6;
    int c  = blockIdx.x & 7;
    int nb = blockIdx.x >> 3;            // 0..999
    int f2 = lane & 3;
    int es = lane >> 2;                  // 0..15

    const float2* gsl2 = FIRST ? ((const float2*)emb + c * 4)
                               : (const float2*)(gT + (size_t)c * NN * 8);
    float2* asl2 = (float2*)(aggT + (size_t)c * NN * 8);

    // streaming L2 warm of this XCD's gather source
    float pf = 0.f;
    if (FIRST) {
        int i = nb * 164 + threadIdx.x;
        if (threadIdx.x < 164 && i < VOCAB * 16) {
            float4 v = ((const float4*)emb)[i];
            pf = v.x * 0.0f;
        }
    } else {
        if (threadIdx.x < 200) {
            int i = nb * 200 + threadIdx.x;   // 1000*200 = NN*2 float4 exactly
            float4 v = ((const float4*)(gT + (size_t)c * NN * 8))[i];
            pf = v.x * 0.0f;
        }
    }

    int n0 = nb * 100 + wave * 25;
    int li = lane < 25 ? lane : 25;
    int sv = start[n0 + li];             // start[n0..n0+25] distributed over lanes

    for (int j = 0; j < 25; ++j) {
        int s0 = __shfl(sv, j, 64);
        int s1 = __shfl(sv, j + 1, 64);
        float ax = pf, ay = 0.f;
        for (int i0 = s0; i0 < s1; i0 += 32) {
            int e0 = i0 + es, e1 = e0 + 16;
            bool g0 = e0 < s1, g1 = e1 < s1;
            int c0 = 0, c1 = 0;
            if (g0) c0 = csr[e0];
            if (g1) c1 = csr[e1];
            if (FIRST) { c0 = x[c0]; c1 = x[c1]; }
            float2 v0, v1;
            if (FIRST) {
                v0 = gsl2[(size_t)c0 * 32 + f2];
                v1 = gsl2[(size_t)c1 * 32 + f2];
            } else {
                v0 = gsl2[(size_t)c0 * 4 + f2];
                v1 = gsl2[(size_t)c1 * 4 + f2];
            }
            ax += (g0 ? v0.x : 0.f) + (g1 ? v1.x : 0.f);
            ay += (g0 ? v0.y : 0.f) + (g1 ? v1.y : 0.f);
        }
        // reduce over es (lane bits 2..5); f2 (bits 0..1) preserved
        ax += __shfl_xor(ax, 4, 64);  ay += __shfl_xor(ay, 4, 64);
        ax += __shfl_xor(ax, 8, 64);  ay += __shfl_xor(ay, 8, 64);
        ax += __shfl_xor(ax, 16, 64); ay += __shfl_xor(ay, 16, 64);
        ax += __shfl_xor(ax, 32, 64); ay += __shfl_xor(ay, 32, 64);
        int n = n0 + j;
        if (lane < 4) { float2 o; o.x = ax; o.y = ay; asl2[(size_t)n * 4 + lane] = o; }
    }
}

// ---------------- layer-1 linear: agg slabs + root from emb[x[n]]; out -> slabs ----------------
__global__ void __launch_bounds__(256) k_lin1(const int* __restrict__ start,
        const float* __restrict__ aggT, const int* __restrict__ x,
        const float4* __restrict__ emb4,
        const float4* __restrict__ Wl, const float* __restrict__ bl,
        const float4* __restrict__ Wr, float* __restrict__ outSlab) {
    __shared__ float sA[64][68];
    __shared__ float sR[64][68];
    int tid = threadIdx.x;
    int lane = tid & 63, wave = tid >> 6;
    int n0 = blockIdx.x * 64;
    {
        int arr = tid >> 7;          // 0: agg (slabs), 1: root (emb)
        int idx = tid & 127;
        int nl = idx >> 1;
        int h = idx & 1;
        int n = min(n0 + nl, NN - 1);
        if (arr == 0) {
#pragma unroll
            for (int c = 0; c < 8; ++c) {
                float4 v = *(const float4*)(aggT + (size_t)c * NN * 8 + (size_t)n * 8 + h * 4);
                *(float4*)(&sA[nl][c * 8 + h * 4]) = v;
            }
        } else {
            int xi = x[n];
#pragma unroll
            for (int k = 0; k < 8; ++k) {
                float4 v = emb4[(size_t)xi * 16 + h * 8 + k];
                *(float4*)(&sR[nl][h * 32 + k * 4]) = v;
            }
        }
    }
    __syncthreads();

    float4 wl[16], wr[16];
#pragma unroll
    for (int i = 0; i < 16; ++i) {
        wl[i] = Wl[lane * 16 + i];
        wr[i] = Wr[lane * 16 + i];
    }
    float bias = bl[lane];

    for (int j = 0; j < 16; ++j) {
        int nl = wave * 16 + j;
        int n = n0 + nl;
        if (n >= NN) break;
        int s0 = start[n], s1 = start[n + 1];
        float inv = 1.0f / (float)max(s1 - s0, 1);
        const float4* ap = (const float4*)&sA[nl][0];
        const float4* rp = (const float4*)&sR[nl][0];
        float a = 0.f, r = 0.f;
#pragma unroll
        for (int k = 0; k < 16; ++k) {
            float4 a4 = ap[k], h4 = rp[k];
            a += a4.x * wl[k].x + a4.y * wl[k].y + a4.z * wl[k].z + a4.w * wl[k].w;
            r += h4.x * wr[k].x + h4.y * wr[k].y + h4.z * wr[k].z + h4.w * wr[k].w;
        }
        float v = fmaxf(a * inv + bias + r, 0.f);
        outSlab[(size_t)(lane >> 3) * NN * 8 + (size_t)n * 8 + (lane & 7)] = v;
    }
}

// ---------------- layer-2 linear + fused per-graph pooling (batch sorted) ----------------
__global__ void __launch_bounds__(256) k_lin2(const int* __restrict__ start,
        const float* __restrict__ aggT, const float* __restrict__ rootT,
        const float4* __restrict__ Wl, const float* __restrict__ bl,
        const float4* __restrict__ Wr, const int* __restrict__ batch,
        float* __restrict__ pooled) {
    __shared__ float sA[64][68];
    __shared__ float sR[64][68];
    int tid = threadIdx.x;
    int lane = tid & 63, wave = tid >> 6;
    int n0 = blockIdx.x * 64;
    {
        int arr = tid >> 7;
        int idx = tid & 127;
        int nl = idx >> 1;
        int h = idx & 1;
        int n = min(n0 + nl, NN - 1);
        const float* srcp = arr ? rootT : aggT;
        float* dstp = arr ? &sR[0][0] : &sA[0][0];
#pragma unroll
        for (int c = 0; c < 8; ++c) {
            float4 v = *(const float4*)(srcp + (size_t)c * NN * 8 + (size_t)n * 8 + h * 4);
            *(float4*)(dstp + nl * 68 + c * 8 + h * 4) = v;
        }
    }
    __syncthreads();

    float4 wl[16], wr[16];
#pragma unroll
    for (int i = 0; i < 16; ++i) {
        wl[i] = Wl[lane * 16 + i];
        wr[i] = Wr[lane * 16 + i];
    }
    float bias = bl[lane];

    int bv = batch[min(n0 + lane, NN - 1)];
    float rsum = 0.f;
    int gcur = __shfl(bv, wave * 16, 64);

    for (int j = 0; j < 16; ++j) {
        int nl = wave * 16 + j;
        int n = n0 + nl;
        if (n >= NN) break;
        int s0 = start[n], s1 = start[n + 1];
        float inv = 1.0f / (float)max(s1 - s0, 1);
        const float4* ap = (const float4*)&sA[nl][0];
        const float4* rp = (const float4*)&sR[nl][0];
        float a = 0.f, r = 0.f;
#pragma unroll
        for (int k = 0; k < 16; ++k) {
            float4 a4 = ap[k], h4 = rp[k];
            a += a4.x * wl[k].x + a4.y * wl[k].y + a4.z * wl[k].z + a4.w * wl[k].w;
            r += h4.x * wr[k].x + h4.y * wr[k].y + h4.z * wr[k].z + h4.w * wr[k].w;
        }
        float v = fmaxf(a * inv + bias + r, 0.f);
        int g = __shfl(bv, wave * 16 + j, 64);   // wave-uniform
        if (g != gcur) {
            atomAddF(&pooled[(size_t)gcur * D + lane], rsum);
            rsum = 0.f;
            gcur = g;
        }
        rsum += v;
    }
    atomAddF(&pooled[(size_t)gcur * D + lane], rsum);
}

// ---------------- readout ----------------
__global__ void __launch_bounds__(256) k_bounds(const int* __restrict__ batch, int* __restrict__ gs) {
    int n = blockIdx.x * blockDim.x + threadIdx.x;
    if (n >= NN) return;
    int b = batch[n];
    if (n == 0) {
        for (int g = 0; g <= b; ++g) gs[g] = 0;
    } else {
        int bp = batch[n - 1];
        for (int g = bp + 1; g <= b; ++g) gs[g] = n;
    }
    if (n == NN - 1) {
        for (int g = b + 1; g <= NG; ++g) gs[g] = NN;
    }
}

__global__ void __launch_bounds__(256) k_out(const int* __restrict__ gs,
        const float* __restrict__ pooled, const float* __restrict__ Wout,
        const float* __restrict__ bout, float* __restrict__ out) {
    int lane = threadIdx.x & 63;
    int wave = threadIdx.x >> 6;
    int g = blockIdx.x * 4 + wave;       // 512 blocks
    int s0 = gs[g], s1 = gs[g + 1];
    float p = pooled[(size_t)g * D + lane] / (float)max(s1 - s0, 1);
    float c0 = p * Wout[lane];
    float c1 = p * Wout[D + lane];
#pragma unroll
    for (int off = 32; off > 0; off >>= 1) {
        c0 += __shfl_down(c0, off, 64);
        c1 += __shfl_down(c1, off, 64);
    }
    if (lane == 0) {
        out[g * C + 0] = c0 + bout[0];
        out[g * C + 1] = c1 + bout[1];
    }
}

extern "C" void kernel_launch(void* const* d_in, const int* in_sizes, int n_in,
                              void* d_out, int out_size, void* d_ws, size_t ws_size,
                              hipStream_t stream) {
    const int*   x     = (const int*)d_in[0];
    const int*   src   = (const int*)d_in[1];
    const int*   dst   = src + NE;
    const int*   batch = (const int*)d_in[2];
    const float* emb   = (const float*)d_in[3];
    const float* W1l   = (const float*)d_in[4];
    const float* b1l   = (const float*)d_in[5];
    const float* W1r   = (const float*)d_in[6];
    const float* W2l   = (const float*)d_in[7];
    const float* b2l   = (const float*)d_in[8];
    const float* W2r   = (const float*)d_in[9];
    const float* Wout  = (const float*)d_in[10];
    const float* bout  = (const float*)d_in[11];
    float* out = (float*)d_out;

    float* T0     = (float*)d_ws;                 // NN*64  h1 slabs
    float* TA     = T0 + (size_t)NN * 64;         // NN*64  agg slabs
    float* pooled = TA + (size_t)NN * 64;         // NG*64
    int* deg    = (int*)(pooled + (size_t)NG * 64);  // NN   (contiguous w/ pooled for memset)
    int* startA = deg + NN;                          // NN+1
    int* cursor = startA + NN + 1;                   // NN
    int* locx   = cursor + NN;                       // NN
    int* bsum   = locx + NN;                         // NB
    int* boff   = bsum + NB;                         // NB
    int* gs     = boff + NB;                         // NG+1
    int* csr    = gs + NG + 1;                       // NE

    hipMemsetAsync(pooled, 0, ((size_t)NG * 64 + NN) * sizeof(float), stream);

    k_hist <<<(NE + 255) / 256, 256, 0, stream>>>(dst, deg);
    k_scan1<<<NB, 256, 0, stream>>>(deg, locx, bsum);
    k_scan2<<<1, 256, 0, stream>>>(bsum, boff);
    k_scan3<<<NB, SB, 0, stream>>>(locx, boff, startA, cursor);
    k_build<<<(NE + 255) / 256, 256, 0, stream>>>(src, dst, cursor, csr);
    k_bounds<<<(NN + 255) / 256, 256, 0, stream>>>(batch, gs);

    // ---- layer 1 (embedding fused into gather) ----
    k_agg<true><<<8000, 256, 0, stream>>>(startA, csr, x, emb, nullptr, TA);
    k_lin1<<<(NN + 63) / 64, 256, 0, stream>>>(startA, TA, x, (const float4*)emb,
                                               (const float4*)W1l, b1l,
                                               (const float4*)W1r, T0);
    // ---- layer 2 ----
    k_agg<false><<<8000, 256, 0, stream>>>(startA, csr, nullptr, nullptr, T0, TA);
    k_lin2<<<(NN + 63) / 64, 256, 0, stream>>>(startA, TA, T0,
                                               (const float4*)W2l, b2l,
                                               (const float4*)W2r, batch, pooled);

    // ---- readout ----
    k_out<<<NG / 4, 256, 0, stream>>>(gs, pooled, Wout, bout, out);
}

// Round 8
// 657.391 us; speedup vs baseline: 1.1251x; 1.1251x over previous
//
#include <hip/hip_runtime.h>

#define NN 100000
#define NE 1200000
#define NG 2048
#define VOCAB 10000
#define D 64
#define C 2

#define SB 512
#define NB ((NN + SB - 1) / SB)   // 196 scan blocks

__device__ __forceinline__ int atomAddI(int* p, int v) {
    return __hip_atomic_fetch_add(p, v, __ATOMIC_RELAXED, __HIP_MEMORY_SCOPE_AGENT);
}
__device__ __forceinline__ void atomAddF(float* p, float v) {
    __hip_atomic_fetch_add(p, v, __ATOMIC_RELAXED, __HIP_MEMORY_SCOPE_AGENT);
}

// ---------------- CSR build ----------------
__global__ void __launch_bounds__(256) k_hist(const int* __restrict__ dst, int* __restrict__ deg) {
    int e = blockIdx.x * blockDim.x + threadIdx.x;
    if (e < NE) atomAddI(&deg[dst[e]], 1);
}

__global__ void __launch_bounds__(256) k_scan1(const int* __restrict__ deg, int* __restrict__ locx,
                        int* __restrict__ bsum) {
    __shared__ int sm[256];
    int t = threadIdx.x;
    int i0 = blockIdx.x * SB + 2 * t;
    int d0 = (i0 < NN) ? deg[i0] : 0;
    int d1 = (i0 + 1 < NN) ? deg[i0 + 1] : 0;
    int s = d0 + d1;
    sm[t] = s;
    __syncthreads();
    for (int off = 1; off < 256; off <<= 1) {
        int v = (t >= off) ? sm[t - off] : 0;
        __syncthreads();
        sm[t] += v;
        __syncthreads();
    }
    int ex = sm[t] - s;
    if (i0 < NN) locx[i0] = ex;
    if (i0 + 1 < NN) locx[i0 + 1] = ex + d0;
    if (t == 255) bsum[blockIdx.x] = sm[255];
}

// scan3 with fused block-offset reduction (replaces scan2+scan3)
__global__ void __launch_bounds__(512) k_scan3(const int* __restrict__ locx, const int* __restrict__ bsum,
                        int* __restrict__ start, int* __restrict__ cursor) {
    __shared__ int red[256];
    int t = threadIdx.x;
    if (t < 256) red[t] = (t < blockIdx.x && t < NB) ? bsum[t] : 0;
    __syncthreads();
    for (int off = 128; off > 0; off >>= 1) {
        if (t < off) red[t] += red[t + off];
        __syncthreads();
    }
    int boff = red[0];
    int i = blockIdx.x * SB + t;
    if (i < NN) {
        int v = locx[i] + boff;
        start[i] = v;
        cursor[i] = v;
    }
    if (i == 0) start[NN] = NE;
}

__global__ void __launch_bounds__(256) k_build(const int* __restrict__ src, const int* __restrict__ dst,
                        int* __restrict__ cursor, int* __restrict__ csr_src) {
    int e = blockIdx.x * blockDim.x + threadIdx.x;
    if (e < NE) {
        int pos = atomAddI(&cursor[dst[e]], 1);
        csr_src[pos] = src[e];
    }
}

// ---------------- layer 1, fully fused: agg from emb[x[.]] + lin + ReLU -> h1 slabs ----------------
// emb (2.56 MB) is L2-resident on every XCD -> no chunking. Block = 64 nodes.
// Phase 1: lane = nsub(4 nodes) x f4(16 float4) -> one 1KB coalesced gather instr
// covers 4 edges' full 256B rows. Each lane accumulates its 4 floats privately
// (no cross-lane reduction). inv folded in. Root rows gathered the same way.
// Phase 2: register-resident-W matvec from LDS, write h1 slabs.
__global__ void __launch_bounds__(256) k_l1(const int* __restrict__ start,
        const int* __restrict__ csr, const int* __restrict__ x,
        const float4* __restrict__ emb4,
        const float4* __restrict__ Wl, const float* __restrict__ bl,
        const float4* __restrict__ Wr, float* __restrict__ outSlab) {
    __shared__ float sA[64][72];
    __shared__ float sR[64][72];
    int tid = threadIdx.x;
    int lane = tid & 63, wave = tid >> 6;
    int f4 = lane & 15, nsub = lane >> 4;
    int n0 = blockIdx.x * 64;

    // warm this XCD's L2 with emb (each block streams a 13 KB slice)
    {
        int nb8 = blockIdx.x >> 3;   // 0..195 per XCD
        for (int i = tid; i < 832; i += 256) {
            int idx = nb8 * 832 + i;
            if (idx < VOCAB * 16) {
                float4 v = emb4[idx];
                if (v.x == 1e38f) sA[0][0] = v.y;   // never true; keeps the load
            }
        }
    }

    for (int b = 0; b < 4; ++b) {
        int nl = wave * 16 + b * 4 + nsub;      // 0..63
        int n = n0 + nl;
        bool ok = n < NN;
        int nc = ok ? n : NN - 1;
        int s0 = start[nc], s1 = start[nc + 1];
        float inv = 1.0f / (float)max(s1 - s0, 1);
        float4 acc = make_float4(0.f, 0.f, 0.f, 0.f);
        int i = s0;
        for (; i + 2 <= s1; i += 2) {
            int c0 = csr[i], c1 = csr[i + 1];
            int x0 = x[c0], x1 = x[c1];
            float4 v0 = emb4[(size_t)x0 * 16 + f4];
            float4 v1 = emb4[(size_t)x1 * 16 + f4];
            acc.x += v0.x + v1.x; acc.y += v0.y + v1.y;
            acc.z += v0.z + v1.z; acc.w += v0.w + v1.w;
        }
        if (i < s1) {
            float4 v = emb4[(size_t)x[csr[i]] * 16 + f4];
            acc.x += v.x; acc.y += v.y; acc.z += v.z; acc.w += v.w;
        }
        float4 rv = emb4[(size_t)x[nc] * 16 + f4];
        acc.x *= inv; acc.y *= inv; acc.z *= inv; acc.w *= inv;
        *(float4*)(&sA[nl][f4 * 4]) = acc;
        *(float4*)(&sR[nl][f4 * 4]) = rv;
    }
    __syncthreads();

    float4 wl[16], wr[16];
#pragma unroll
    for (int i = 0; i < 16; ++i) {
        wl[i] = Wl[lane * 16 + i];
        wr[i] = Wr[lane * 16 + i];
    }
    float bias = bl[lane];

    for (int j = 0; j < 16; ++j) {
        int nl = wave * 16 + j;
        int n = n0 + nl;
        if (n >= NN) break;
        const float4* ap = (const float4*)&sA[nl][0];
        const float4* rp = (const float4*)&sR[nl][0];
        float a = 0.f, r = 0.f;
#pragma unroll
        for (int k = 0; k < 16; ++k) {
            float4 a4 = ap[k], h4 = rp[k];
            a += a4.x * wl[k].x + a4.y * wl[k].y + a4.z * wl[k].z + a4.w * wl[k].w;
            r += h4.x * wr[k].x + h4.y * wr[k].y + h4.z * wr[k].z + h4.w * wr[k].w;
        }
        float v = fmaxf(a + bias + r, 0.f);
        outSlab[(size_t)(lane >> 3) * NN * 8 + (size_t)n * 8 + (lane & 7)] = v;
    }
}

// ---------------- layer-2 chunked aggregate: no-shfl layout ----------------
// chunk-per-XCD (c = blockIdx.x & 7). lane = nsub(8 nodes) x f(8): each lane
// privately accumulates feature f of node nsub -> zero cross-lane ops, 8 nodes
// progress in parallel per wave. Block covers 128 nodes (4 waves x 4 batches).
// 1/deg folded into the store.
__global__ void __launch_bounds__(256) k_agg2(const int* __restrict__ start,
        const int* __restrict__ csr, const float* __restrict__ gT,
        float* __restrict__ aggT) {
    int tid = threadIdx.x;
    int lane = tid & 63, wave = tid >> 6;
    int c  = blockIdx.x & 7;
    int nb = blockIdx.x >> 3;            // 0..781
    int f = lane & 7, nsub = lane >> 3;  // nsub 0..7
    const float* gsl = gT + (size_t)c * NN * 8;
    float* asl = aggT + (size_t)c * NN * 8;

    // streaming L2 warm of this block's slab slice
    float pf = 0.f;
    {
        int i = nb * 256 + tid;
        if (i < NN * 2) {
            float4 v = ((const float4*)gsl)[i];
            pf = v.x * 0.0f;
        }
    }

    int n0 = nb * 128;
    for (int b = 0; b < 4; ++b) {
        int n = n0 + wave * 32 + b * 8 + nsub;
        if (n >= NN) break;
        int s0 = start[n], s1 = start[n + 1];
        float inv = 1.0f / (float)max(s1 - s0, 1);
        float acc = pf;
        int i = s0;
        for (; i + 2 <= s1; i += 2) {
            int c0 = csr[i], c1 = csr[i + 1];
            float v0 = gsl[(size_t)c0 * 8 + f];
            float v1 = gsl[(size_t)c1 * 8 + f];
            acc += v0 + v1;
        }
        if (i < s1) acc += gsl[(size_t)csr[i] * 8 + f];
        asl[(size_t)n * 8 + f] = acc * inv;
    }
}

// ---------------- layer-2 linear + fused per-graph pooling (batch sorted) ----------------
__global__ void __launch_bounds__(256) k_lin2(const float* __restrict__ aggT,
        const float* __restrict__ rootT,
        const float4* __restrict__ Wl, const float* __restrict__ bl,
        const float4* __restrict__ Wr, const int* __restrict__ batch,
        float* __restrict__ pooled) {
    __shared__ float sA[64][72];
    __shared__ float sR[64][72];
    int tid = threadIdx.x;
    int lane = tid & 63, wave = tid >> 6;
    int n0 = blockIdx.x * 64;
    {
        int arr = tid >> 7;
        int idx = tid & 127;
        int nl = idx >> 1;
        int h = idx & 1;
        int n = min(n0 + nl, NN - 1);
        const float* srcp = arr ? rootT : aggT;
        float* dstp = arr ? &sR[0][0] : &sA[0][0];
#pragma unroll
        for (int c = 0; c < 8; ++c) {
            float4 v = *(const float4*)(srcp + (size_t)c * NN * 8 + (size_t)n * 8 + h * 4);
            *(float4*)(dstp + nl * 72 + c * 8 + h * 4) = v;
        }
    }
    __syncthreads();

    float4 wl[16], wr[16];
#pragma unroll
    for (int i = 0; i < 16; ++i) {
        wl[i] = Wl[lane * 16 + i];
        wr[i] = Wr[lane * 16 + i];
    }
    float bias = bl[lane];

    int bv = batch[min(n0 + lane, NN - 1)];
    float rsum = 0.f;
    int gcur = __shfl(bv, wave * 16, 64);

    for (int j = 0; j < 16; ++j) {
        int nl = wave * 16 + j;
        int n = n0 + nl;
        if (n >= NN) break;
        const float4* ap = (const float4*)&sA[nl][0];
        const float4* rp = (const float4*)&sR[nl][0];
        float a = 0.f, r = 0.f;
#pragma unroll
        for (int k = 0; k < 16; ++k) {
            float4 a4 = ap[k], h4 = rp[k];
            a += a4.x * wl[k].x + a4.y * wl[k].y + a4.z * wl[k].z + a4.w * wl[k].w;
            r += h4.x * wr[k].x + h4.y * wr[k].y + h4.z * wr[k].z + h4.w * wr[k].w;
        }
        float v = fmaxf(a + bias + r, 0.f);
        int g = __shfl(bv, wave * 16 + j, 64);   // wave-uniform
        if (g != gcur) {
            atomAddF(&pooled[(size_t)gcur * D + lane], rsum);
            rsum = 0.f;
            gcur = g;
        }
        rsum += v;
    }
    atomAddF(&pooled[(size_t)gcur * D + lane], rsum);
}

// ---------------- readout ----------------
__global__ void __launch_bounds__(256) k_bounds(const int* __restrict__ batch, int* __restrict__ gs) {
    int n = blockIdx.x * blockDim.x + threadIdx.x;
    if (n >= NN) return;
    int b = batch[n];
    if (n == 0) {
        for (int g = 0; g <= b; ++g) gs[g] = 0;
    } else {
        int bp = batch[n - 1];
        for (int g = bp + 1; g <= b; ++g) gs[g] = n;
    }
    if (n == NN - 1) {
        for (int g = b + 1; g <= NG; ++g) gs[g] = NN;
    }
}

__global__ void __launch_bounds__(256) k_out(const int* __restrict__ gs,
        const float* __restrict__ pooled, const float* __restrict__ Wout,
        const float* __restrict__ bout, float* __restrict__ out) {
    int lane = threadIdx.x & 63;
    int wave = threadIdx.x >> 6;
    int g = blockIdx.x * 4 + wave;       // 512 blocks
    int s0 = gs[g], s1 = gs[g + 1];
    float p = pooled[(size_t)g * D + lane] / (float)max(s1 - s0, 1);
    float c0 = p * Wout[lane];
    float c1 = p * Wout[D + lane];
#pragma unroll
    for (int off = 32; off > 0; off >>= 1) {
        c0 += __shfl_down(c0, off, 64);
        c1 += __shfl_down(c1, off, 64);
    }
    if (lane == 0) {
        out[g * C + 0] = c0 + bout[0];
        out[g * C + 1] = c1 + bout[1];
    }
}

extern "C" void kernel_launch(void* const* d_in, const int* in_sizes, int n_in,
                              void* d_out, int out_size, void* d_ws, size_t ws_size,
                              hipStream_t stream) {
    const int*   x     = (const int*)d_in[0];
    const int*   src   = (const int*)d_in[1];
    const int*   dst   = src + NE;
    const int*   batch = (const int*)d_in[2];
    const float* emb   = (const float*)d_in[3];
    const float* W1l   = (const float*)d_in[4];
    const float* b1l   = (const float*)d_in[5];
    const float* W1r   = (const float*)d_in[6];
    const float* W2l   = (const float*)d_in[7];
    const float* b2l   = (const float*)d_in[8];
    const float* W2r   = (const float*)d_in[9];
    const float* Wout  = (const float*)d_in[10];
    const float* bout  = (const float*)d_in[11];
    float* out = (float*)d_out;

    float* T0     = (float*)d_ws;                 // NN*64  h1 slabs
    float* TA     = T0 + (size_t)NN * 64;         // NN*64  agg slabs
    float* pooled = TA + (size_t)NN * 64;         // NG*64
    int* deg    = (int*)(pooled + (size_t)NG * 64);  // NN (contiguous w/ pooled for memset)
    int* startA = deg + NN;                          // NN+1
    int* cursor = startA + NN + 1;                   // NN
    int* locx   = cursor + NN;                       // NN
    int* bsum   = locx + NN;                         // NB
    int* gs     = bsum + NB;                         // NG+1
    int* csr    = gs + NG + 1;                       // NE

    hipMemsetAsync(pooled, 0, ((size_t)NG * 64 + NN) * sizeof(float), stream);

    k_hist <<<(NE + 255) / 256, 256, 0, stream>>>(dst, deg);
    k_scan1<<<NB, 256, 0, stream>>>(deg, locx, bsum);
    k_scan3<<<NB, SB, 0, stream>>>(locx, bsum, startA, cursor);
    k_build<<<(NE + 255) / 256, 256, 0, stream>>>(src, dst, cursor, csr);
    k_bounds<<<(NN + 255) / 256, 256, 0, stream>>>(batch, gs);

    // ---- layer 1: one fused kernel (agg from emb + lin + ReLU) -> h1 slabs ----
    k_l1<<<(NN + 63) / 64, 256, 0, stream>>>(startA, csr, x, (const float4*)emb,
                                             (const float4*)W1l, b1l,
                                             (const float4*)W1r, T0);
    // ---- layer 2 ----
    k_agg2<<<((NN + 127) / 128) * 8, 256, 0, stream>>>(startA, csr, T0, TA);
    k_lin2<<<(NN + 63) / 64, 256, 0, stream>>>(TA, T0,
                                               (const float4*)W2l, b2l,
                                               (const float4*)W2r, batch, pooled);

    // ---- readout ----
    k_out<<<NG / 4, 256, 0, stream>>>(gs, pooled, Wout, bout, out);
}

// Round 9
// 624.158 us; speedup vs baseline: 1.1851x; 1.0532x over previous
//
#include <hip/hip_runtime.h>

#define NN 100000
#define NE 1200000
#define NG 2048
#define VOCAB 10000
#define D 64
#define C 2

#define SB 512
#define NB ((NN + SB - 1) / SB)   // 196 scan blocks

__device__ __forceinline__ int atomAddI(int* p, int v) {
    return __hip_atomic_fetch_add(p, v, __ATOMIC_RELAXED, __HIP_MEMORY_SCOPE_AGENT);
}
__device__ __forceinline__ void atomAddF(float* p, float v) {
    __hip_atomic_fetch_add(p, v, __ATOMIC_RELAXED, __HIP_MEMORY_SCOPE_AGENT);
}

// ---------------- CSR build ----------------
__global__ void __launch_bounds__(256) k_hist(const int* __restrict__ dst, int* __restrict__ deg) {
    int e = blockIdx.x * blockDim.x + threadIdx.x;
    if (e < NE) atomAddI(&deg[dst[e]], 1);
}

__global__ void __launch_bounds__(256) k_scan1(const int* __restrict__ deg, int* __restrict__ locx,
                        int* __restrict__ bsum) {
    __shared__ int sm[256];
    int t = threadIdx.x;
    int i0 = blockIdx.x * SB + 2 * t;
    int d0 = (i0 < NN) ? deg[i0] : 0;
    int d1 = (i0 + 1 < NN) ? deg[i0 + 1] : 0;
    int s = d0 + d1;
    sm[t] = s;
    __syncthreads();
    for (int off = 1; off < 256; off <<= 1) {
        int v = (t >= off) ? sm[t - off] : 0;
        __syncthreads();
        sm[t] += v;
        __syncthreads();
    }
    int ex = sm[t] - s;
    if (i0 < NN) locx[i0] = ex;
    if (i0 + 1 < NN) locx[i0 + 1] = ex + d0;
    if (t == 255) bsum[blockIdx.x] = sm[255];
}

// scan3 with fused block-offset reduction
__global__ void __launch_bounds__(512) k_scan3(const int* __restrict__ locx, const int* __restrict__ bsum,
                        int* __restrict__ start, int* __restrict__ cursor) {
    __shared__ int red[256];
    int t = threadIdx.x;
    if (t < 256) red[t] = (t < blockIdx.x && t < NB) ? bsum[t] : 0;
    __syncthreads();
    for (int off = 128; off > 0; off >>= 1) {
        if (t < off) red[t] += red[t + off];
        __syncthreads();
    }
    int boff = red[0];
    int i = blockIdx.x * SB + t;
    if (i < NN) {
        int v = locx[i] + boff;
        start[i] = v;
        cursor[i] = v;
    }
    if (i == 0) start[NN] = NE;
}

__global__ void __launch_bounds__(256) k_build(const int* __restrict__ src, const int* __restrict__ dst,
                        int* __restrict__ cursor, int* __restrict__ csr_src) {
    int e = blockIdx.x * blockDim.x + threadIdx.x;
    if (e < NE) {
        int pos = atomAddI(&cursor[dst[e]], 1);
        csr_src[pos] = src[e];
    }
}

// ---------------- embedding -> h0 slabs T0[c][n][8] ----------------
__global__ void __launch_bounds__(256) k_embedT(const int* __restrict__ x, const float* __restrict__ emb,
                         float* __restrict__ T0) {
    int tid = blockIdx.x * blockDim.x + threadIdx.x;
    if (tid >= NN * 64) return;
    int c = tid / (NN * 8);
    int r = tid % (NN * 8);
    int n = r >> 3, f = r & 7;
    T0[tid] = emb[(size_t)x[n] * 64 + c * 8 + f];
}

// ---------------- chunked aggregate: no-shfl layout, unroll 4 ----------------
// chunk-per-XCD (c = blockIdx.x & 7). lane = nsub(8 nodes) x f(8): each lane
// privately accumulates feature f of node nsub; zero cross-lane ops; 8 nodes in
// parallel per wave; 4 independent gather chains in flight. 1/deg folded in.
__global__ void __launch_bounds__(256) k_agg2(const int* __restrict__ start,
        const int* __restrict__ csr, const float* __restrict__ gT,
        float* __restrict__ aggT) {
    int tid = threadIdx.x;
    int lane = tid & 63, wave = tid >> 6;
    int c  = blockIdx.x & 7;
    int nb = blockIdx.x >> 3;            // 0..781
    int f = lane & 7, nsub = lane >> 3;  // nsub 0..7
    const float* gsl = gT + (size_t)c * NN * 8;
    float* asl = aggT + (size_t)c * NN * 8;

    // streaming L2 warm of this block's slab slice
    float pf = 0.f;
    {
        int i = nb * 256 + tid;
        if (i < NN * 2) {
            float4 v = ((const float4*)gsl)[i];
            pf = v.x * 0.0f;
        }
    }

    int n0 = nb * 128;
    for (int b = 0; b < 4; ++b) {
        int n = n0 + wave * 32 + b * 8 + nsub;
        if (n >= NN) break;
        int s0 = start[n], s1 = start[n + 1];
        float inv = 1.0f / (float)max(s1 - s0, 1);
        float acc = pf, acc2 = 0.f;
        int i = s0;
        for (; i + 4 <= s1; i += 4) {
            int c0 = csr[i], c1 = csr[i + 1], c2 = csr[i + 2], c3 = csr[i + 3];
            float v0 = gsl[(size_t)c0 * 8 + f];
            float v1 = gsl[(size_t)c1 * 8 + f];
            float v2 = gsl[(size_t)c2 * 8 + f];
            float v3 = gsl[(size_t)c3 * 8 + f];
            acc += v0 + v1;
            acc2 += v2 + v3;
        }
        for (; i < s1; ++i) acc += gsl[(size_t)csr[i] * 8 + f];
        asl[(size_t)n * 8 + f] = (acc + acc2) * inv;
    }
}

// ---------------- SAGE linear (+ReLU); POOL: fused per-graph mean-pool ----------------
// Block = 64 nodes; stage agg+root slabs into LDS coalesced; lane d holds
// Wl/Wr row d in registers. !POOL: write h-out slabs (may alias rootT: all
// reads of this block's rows happen in staging, before the writes).
template<bool POOL>
__global__ void __launch_bounds__(256) k_lin(const float* __restrict__ aggT,
        const float* rootT,
        const float4* __restrict__ Wl, const float* __restrict__ bl,
        const float4* __restrict__ Wr, const int* __restrict__ batch,
        float* __restrict__ outp) {
    __shared__ float sA[64][72];
    __shared__ float sR[64][72];
    int tid = threadIdx.x;
    int lane = tid & 63, wave = tid >> 6;
    int n0 = blockIdx.x * 64;
    {
        int arr = tid >> 7;
        int idx = tid & 127;
        int nl = idx >> 1;
        int h = idx & 1;
        int n = min(n0 + nl, NN - 1);
        const float* srcp = arr ? rootT : aggT;
        float* dstp = arr ? &sR[0][0] : &sA[0][0];
#pragma unroll
        for (int c = 0; c < 8; ++c) {
            float4 v = *(const float4*)(srcp + (size_t)c * NN * 8 + (size_t)n * 8 + h * 4);
            *(float4*)(dstp + nl * 72 + c * 8 + h * 4) = v;
        }
    }
    __syncthreads();

    float4 wl[16], wr[16];
#pragma unroll
    for (int i = 0; i < 16; ++i) {
        wl[i] = Wl[lane * 16 + i];
        wr[i] = Wr[lane * 16 + i];
    }
    float bias = bl[lane];

    int bv = 0, gcur = 0;
    float rsum = 0.f;
    if (POOL) {
        bv = batch[min(n0 + lane, NN - 1)];
        gcur = __shfl(bv, wave * 16, 64);
    }

    for (int j = 0; j < 16; ++j) {
        int nl = wave * 16 + j;
        int n = n0 + nl;
        if (n >= NN) break;
        const float4* ap = (const float4*)&sA[nl][0];
        const float4* rp = (const float4*)&sR[nl][0];
        float a = 0.f, r = 0.f;
#pragma unroll
        for (int k = 0; k < 16; ++k) {
            float4 a4 = ap[k], h4 = rp[k];
            a += a4.x * wl[k].x + a4.y * wl[k].y + a4.z * wl[k].z + a4.w * wl[k].w;
            r += h4.x * wr[k].x + h4.y * wr[k].y + h4.z * wr[k].z + h4.w * wr[k].w;
        }
        float v = fmaxf(a + bias + r, 0.f);
        if (POOL) {
            int g = __shfl(bv, wave * 16 + j, 64);   // wave-uniform
            if (g != gcur) {
                atomAddF(&outp[(size_t)gcur * D + lane], rsum);
                rsum = 0.f;
                gcur = g;
            }
            rsum += v;
        } else {
            outp[(size_t)(lane >> 3) * NN * 8 + (size_t)n * 8 + (lane & 7)] = v;
        }
    }
    if (POOL) atomAddF(&outp[(size_t)gcur * D + lane], rsum);
}

// ---------------- readout ----------------
__global__ void __launch_bounds__(256) k_bounds(const int* __restrict__ batch, int* __restrict__ gs) {
    int n = blockIdx.x * blockDim.x + threadIdx.x;
    if (n >= NN) return;
    int b = batch[n];
    if (n == 0) {
        for (int g = 0; g <= b; ++g) gs[g] = 0;
    } else {
        int bp = batch[n - 1];
        for (int g = bp + 1; g <= b; ++g) gs[g] = n;
    }
    if (n == NN - 1) {
        for (int g = b + 1; g <= NG; ++g) gs[g] = NN;
    }
}

__global__ void __launch_bounds__(256) k_out(const int* __restrict__ gs,
        const float* __restrict__ pooled, const float* __restrict__ Wout,
        const float* __restrict__ bout, float* __restrict__ out) {
    int lane = threadIdx.x & 63;
    int wave = threadIdx.x >> 6;
    int g = blockIdx.x * 4 + wave;       // 512 blocks
    int s0 = gs[g], s1 = gs[g + 1];
    float p = pooled[(size_t)g * D + lane] / (float)max(s1 - s0, 1);
    float c0 = p * Wout[lane];
    float c1 = p * Wout[D + lane];
#pragma unroll
    for (int off = 32; off > 0; off >>= 1) {
        c0 += __shfl_down(c0, off, 64);
        c1 += __shfl_down(c1, off, 64);
    }
    if (lane == 0) {
        out[g * C + 0] = c0 + bout[0];
        out[g * C + 1] = c1 + bout[1];
    }
}

extern "C" void kernel_launch(void* const* d_in, const int* in_sizes, int n_in,
                              void* d_out, int out_size, void* d_ws, size_t ws_size,
                              hipStream_t stream) {
    const int*   x     = (const int*)d_in[0];
    const int*   src   = (const int*)d_in[1];
    const int*   dst   = src + NE;
    const int*   batch = (const int*)d_in[2];
    const float* emb   = (const float*)d_in[3];
    const float* W1l   = (const float*)d_in[4];
    const float* b1l   = (const float*)d_in[5];
    const float* W1r   = (const float*)d_in[6];
    const float* W2l   = (const float*)d_in[7];
    const float* b2l   = (const float*)d_in[8];
    const float* W2r   = (const float*)d_in[9];
    const float* Wout  = (const float*)d_in[10];
    const float* bout  = (const float*)d_in[11];
    float* out = (float*)d_out;

    float* T0     = (float*)d_ws;                 // NN*64  h0 slabs -> h1 slabs (in place)
    float* TA     = T0 + (size_t)NN * 64;         // NN*64  agg slabs
    float* pooled = TA + (size_t)NN * 64;         // NG*64
    int* deg    = (int*)(pooled + (size_t)NG * 64);  // NN (contiguous w/ pooled for memset)
    int* startA = deg + NN;                          // NN+1
    int* cursor = startA + NN + 1;                   // NN
    int* locx   = cursor + NN;                       // NN
    int* bsum   = locx + NN;                         // NB
    int* gs     = bsum + NB;                         // NG+1
    int* csr    = gs + NG + 1;                       // NE

    hipMemsetAsync(pooled, 0, ((size_t)NG * 64 + NN) * sizeof(float), stream);

    k_hist  <<<(NE + 255) / 256, 256, 0, stream>>>(dst, deg);
    k_scan1 <<<NB, 256, 0, stream>>>(deg, locx, bsum);
    k_scan3 <<<NB, SB, 0, stream>>>(locx, bsum, startA, cursor);
    k_build <<<(NE + 255) / 256, 256, 0, stream>>>(src, dst, cursor, csr);
    k_bounds<<<(NN + 255) / 256, 256, 0, stream>>>(batch, gs);
    k_embedT<<<(NN * 64 + 255) / 256, 256, 0, stream>>>(x, emb, T0);

    // ---- layer 1 ----
    k_agg2<<<((NN + 127) / 128) * 8, 256, 0, stream>>>(startA, csr, T0, TA);
    k_lin<false><<<(NN + 63) / 64, 256, 0, stream>>>(TA, T0, (const float4*)W1l, b1l,
                                                     (const float4*)W1r, nullptr, T0);
    // ---- layer 2 ----
    k_agg2<<<((NN + 127) / 128) * 8, 256, 0, stream>>>(startA, csr, T0, TA);
    k_lin<true><<<(NN + 63) / 64, 256, 0, stream>>>(TA, T0, (const float4*)W2l, b2l,
                                                    (const float4*)W2r, batch, pooled);

    // ---- readout ----
    k_out<<<NG / 4, 256, 0, stream>>>(gs, pooled, Wout, bout, out);
}

// Round 10
// 537.123 us; speedup vs baseline: 1.3771x; 1.1620x over previous
//
#include <hip/hip_runtime.h>

#define NN 100000
#define NE 1200000
#define NG 2048
#define VOCAB 10000
#define D 64
#define C 2

#define SB 512
#define NB ((NN + SB - 1) / SB)   // 196 scan blocks

__device__ __forceinline__ int atomAddI(int* p, int v) {
    return __hip_atomic_fetch_add(p, v, __ATOMIC_RELAXED, __HIP_MEMORY_SCOPE_AGENT);
}
__device__ __forceinline__ void atomAddF(float* p, float v) {
    __hip_atomic_fetch_add(p, v, __ATOMIC_RELAXED, __HIP_MEMORY_SCOPE_AGENT);
}

// ---------------- CSR build ----------------
__global__ void __launch_bounds__(256) k_hist(const int* __restrict__ dst, int* __restrict__ deg) {
    int e = blockIdx.x * blockDim.x + threadIdx.x;
    if (e < NE) atomAddI(&deg[dst[e]], 1);
}

__global__ void __launch_bounds__(256) k_scan1(const int* __restrict__ deg, int* __restrict__ locx,
                        int* __restrict__ bsum) {
    __shared__ int sm[256];
    int t = threadIdx.x;
    int i0 = blockIdx.x * SB + 2 * t;
    int d0 = (i0 < NN) ? deg[i0] : 0;
    int d1 = (i0 + 1 < NN) ? deg[i0 + 1] : 0;
    int s = d0 + d1;
    sm[t] = s;
    __syncthreads();
    for (int off = 1; off < 256; off <<= 1) {
        int v = (t >= off) ? sm[t - off] : 0;
        __syncthreads();
        sm[t] += v;
        __syncthreads();
    }
    int ex = sm[t] - s;
    if (i0 < NN) locx[i0] = ex;
    if (i0 + 1 < NN) locx[i0 + 1] = ex + d0;
    if (t == 255) bsum[blockIdx.x] = sm[255];
}

// scan3 with fused block-offset reduction
__global__ void __launch_bounds__(512) k_scan3(const int* __restrict__ locx, const int* __restrict__ bsum,
                        int* __restrict__ start, int* __restrict__ cursor) {
    __shared__ int red[256];
    int t = threadIdx.x;
    if (t < 256) red[t] = (t < blockIdx.x && t < NB) ? bsum[t] : 0;
    __syncthreads();
    for (int off = 128; off > 0; off >>= 1) {
        if (t < off) red[t] += red[t + off];
        __syncthreads();
    }
    int boff = red[0];
    int i = blockIdx.x * SB + t;
    if (i < NN) {
        int v = locx[i] + boff;
        start[i] = v;
        cursor[i] = v;
    }
    if (i == 0) start[NN] = NE;
}

__global__ void __launch_bounds__(256) k_build(const int* __restrict__ src, const int* __restrict__ dst,
                        int* __restrict__ cursor, int* __restrict__ csr_src) {
    int e = blockIdx.x * blockDim.x + threadIdx.x;
    if (e < NE) {
        int pos = atomAddI(&cursor[dst[e]], 1);
        csr_src[pos] = src[e];
    }
}

// ---------------- embedding -> h0 slabs T0[c][n][8] ----------------
__global__ void __launch_bounds__(256) k_embedT(const int* __restrict__ x, const float* __restrict__ emb,
                         float* __restrict__ T0) {
    int tid = blockIdx.x * blockDim.x + threadIdx.x;
    if (tid >= NN * 64) return;
    int c = tid / (NN * 8);
    int r = tid % (NN * 8);
    int n = r >> 3, f = r & 7;
    T0[tid] = emb[(size_t)x[n] * 64 + c * 8 + f];
}

// ---------------- chunked aggregate: no-shfl layout, unroll 4 ----------------
__global__ void __launch_bounds__(256) k_agg2(const int* __restrict__ start,
        const int* __restrict__ csr, const float* __restrict__ gT,
        float* __restrict__ aggT) {
    int tid = threadIdx.x;
    int lane = tid & 63, wave = tid >> 6;
    int c  = blockIdx.x & 7;
    int nb = blockIdx.x >> 3;            // 0..781
    int f = lane & 7, nsub = lane >> 3;  // nsub 0..7
    const float* gsl = gT + (size_t)c * NN * 8;
    float* asl = aggT + (size_t)c * NN * 8;

    // streaming L2 warm of this block's slab slice
    float pf = 0.f;
    {
        int i = nb * 256 + tid;
        if (i < NN * 2) {
            float4 v = ((const float4*)gsl)[i];
            pf = v.x * 0.0f;
        }
    }

    int n0 = nb * 128;
    for (int b = 0; b < 4; ++b) {
        int n = n0 + wave * 32 + b * 8 + nsub;
        if (n >= NN) break;
        int s0 = start[n], s1 = start[n + 1];
        float inv = 1.0f / (float)max(s1 - s0, 1);
        float acc = pf, acc2 = 0.f;
        int i = s0;
        for (; i + 4 <= s1; i += 4) {
            int c0 = csr[i], c1 = csr[i + 1], c2 = csr[i + 2], c3 = csr[i + 3];
            float v0 = gsl[(size_t)c0 * 8 + f];
            float v1 = gsl[(size_t)c1 * 8 + f];
            float v2 = gsl[(size_t)c2 * 8 + f];
            float v3 = gsl[(size_t)c3 * 8 + f];
            acc += v0 + v1;
            acc2 += v2 + v3;
        }
        for (; i < s1; ++i) acc += gsl[(size_t)csr[i] * 8 + f];
        asl[(size_t)n * 8 + f] = (acc + acc2) * inv;
    }
}

// ---------------- SAGE linear (+ReLU): one THREAD per node ----------------
// acc[64] in VGPRs; inputs read 32B/chunk per array (software-pipelined one
// chunk ahead); W/bias indices are wave-uniform -> scalar s_loads, FMA takes
// the W operand from SGPR. Zero LDS, no weight register array.
// outT may alias aggT or rootT: each thread reads its own row n completely
// before its stores (stores are the epilogue), and rows are thread-exclusive.
__global__ void __launch_bounds__(256) k_lin3(const float* __restrict__ aggT,
        const float* __restrict__ rootT,
        const float* __restrict__ Wl, const float* __restrict__ bl,
        const float* __restrict__ Wr, float* __restrict__ outT) {
    int tid = blockIdx.x * 256 + threadIdx.x;
    int n = tid < NN ? tid : NN - 1;   // clamp; store guarded

    float acc[64];
#pragma unroll
    for (int d = 0; d < 64; ++d) acc[d] = bl[d];

    const float4* ap = (const float4*)(aggT + (size_t)n * 8);
    const float4* rp = (const float4*)(rootT + (size_t)n * 8);
    const size_t cstep = (size_t)NN * 2;   // chunk stride in float4s

    float4 a0 = ap[0], a1 = ap[1], r0 = rp[0], r1 = rp[1];
    for (int c = 0; c < 8; ++c) {
        float av[8] = {a0.x, a0.y, a0.z, a0.w, a1.x, a1.y, a1.z, a1.w};
        float rv[8] = {r0.x, r0.y, r0.z, r0.w, r1.x, r1.y, r1.z, r1.w};
        if (c < 7) {
            size_t off = (size_t)(c + 1) * cstep;
            a0 = ap[off]; a1 = ap[off + 1];
            r0 = rp[off]; r1 = rp[off + 1];
        }
        const float* wlc = Wl + c * 8;   // row d, cols c*8..c*8+7
        const float* wrc = Wr + c * 8;
#pragma unroll
        for (int d = 0; d < 64; ++d) {
#pragma unroll
            for (int k = 0; k < 8; ++k) {
                acc[d] += av[k] * wlc[d * 64 + k];
                acc[d] += rv[k] * wrc[d * 64 + k];
            }
        }
    }

    if (tid < NN) {
#pragma unroll
        for (int c = 0; c < 8; ++c) {
            float4 o0, o1;
            o0.x = fmaxf(acc[c * 8 + 0], 0.f); o0.y = fmaxf(acc[c * 8 + 1], 0.f);
            o0.z = fmaxf(acc[c * 8 + 2], 0.f); o0.w = fmaxf(acc[c * 8 + 3], 0.f);
            o1.x = fmaxf(acc[c * 8 + 4], 0.f); o1.y = fmaxf(acc[c * 8 + 5], 0.f);
            o1.z = fmaxf(acc[c * 8 + 6], 0.f); o1.w = fmaxf(acc[c * 8 + 7], 0.f);
            float4* op = (float4*)(outT + (size_t)c * NN * 8 + (size_t)n * 8);
            op[0] = o0; op[1] = o1;
        }
    }
}

// ---------------- per-graph mean-pool from h2 slabs (batch sorted) ----------------
__global__ void __launch_bounds__(256) k_pools(const float* __restrict__ hT,
        const int* __restrict__ batch, float* __restrict__ pooled) {
    int lane = threadIdx.x & 63;
    int wave = threadIdx.x >> 6;
    int n0 = blockIdx.x * 256 + wave * 64;
    if (n0 >= NN) return;
    const float* base = hT + (size_t)(lane >> 3) * NN * 8 + (lane & 7);
    int gcur = batch[n0];
    float rsum = 0.f;
    int nend = min(n0 + 64, NN);
    for (int n = n0; n < nend; ++n) {
        float v = base[(size_t)n * 8];
        int g = batch[n];                 // uniform -> scalar load, uniform branch
        if (g != gcur) {
            atomAddF(&pooled[(size_t)gcur * D + lane], rsum);
            rsum = 0.f; gcur = g;
        }
        rsum += v;
    }
    atomAddF(&pooled[(size_t)gcur * D + lane], rsum);
}

// ---------------- readout ----------------
__global__ void __launch_bounds__(256) k_bounds(const int* __restrict__ batch, int* __restrict__ gs) {
    int n = blockIdx.x * blockDim.x + threadIdx.x;
    if (n >= NN) return;
    int b = batch[n];
    if (n == 0) {
        for (int g = 0; g <= b; ++g) gs[g] = 0;
    } else {
        int bp = batch[n - 1];
        for (int g = bp + 1; g <= b; ++g) gs[g] = n;
    }
    if (n == NN - 1) {
        for (int g = b + 1; g <= NG; ++g) gs[g] = NN;
    }
}

__global__ void __launch_bounds__(256) k_out(const int* __restrict__ gs,
        const float* __restrict__ pooled, const float* __restrict__ Wout,
        const float* __restrict__ bout, float* __restrict__ out) {
    int lane = threadIdx.x & 63;
    int wave = threadIdx.x >> 6;
    int g = blockIdx.x * 4 + wave;       // 512 blocks
    int s0 = gs[g], s1 = gs[g + 1];
    float p = pooled[(size_t)g * D + lane] / (float)max(s1 - s0, 1);
    float c0 = p * Wout[lane];
    float c1 = p * Wout[D + lane];
#pragma unroll
    for (int off = 32; off > 0; off >>= 1) {
        c0 += __shfl_down(c0, off, 64);
        c1 += __shfl_down(c1, off, 64);
    }
    if (lane == 0) {
        out[g * C + 0] = c0 + bout[0];
        out[g * C + 1] = c1 + bout[1];
    }
}

extern "C" void kernel_launch(void* const* d_in, const int* in_sizes, int n_in,
                              void* d_out, int out_size, void* d_ws, size_t ws_size,
                              hipStream_t stream) {
    const int*   x     = (const int*)d_in[0];
    const int*   src   = (const int*)d_in[1];
    const int*   dst   = src + NE;
    const int*   batch = (const int*)d_in[2];
    const float* emb   = (const float*)d_in[3];
    const float* W1l   = (const float*)d_in[4];
    const float* b1l   = (const float*)d_in[5];
    const float* W1r   = (const float*)d_in[6];
    const float* W2l   = (const float*)d_in[7];
    const float* b2l   = (const float*)d_in[8];
    const float* W2r   = (const float*)d_in[9];
    const float* Wout  = (const float*)d_in[10];
    const float* bout  = (const float*)d_in[11];
    float* out = (float*)d_out;

    float* T0     = (float*)d_ws;                 // NN*64  h0 -> h1 slabs (in place)
    float* TA     = T0 + (size_t)NN * 64;         // NN*64  agg slabs -> h2 slabs (in place)
    float* pooled = TA + (size_t)NN * 64;         // NG*64
    int* deg    = (int*)(pooled + (size_t)NG * 64);  // NN (contiguous w/ pooled for memset)
    int* startA = deg + NN;                          // NN+1
    int* cursor = startA + NN + 1;                   // NN
    int* locx   = cursor + NN;                       // NN
    int* bsum   = locx + NN;                         // NB
    int* gs     = bsum + NB;                         // NG+1
    int* csr    = gs + NG + 1;                       // NE

    hipMemsetAsync(pooled, 0, ((size_t)NG * 64 + NN) * sizeof(float), stream);

    k_hist  <<<(NE + 255) / 256, 256, 0, stream>>>(dst, deg);
    k_scan1 <<<NB, 256, 0, stream>>>(deg, locx, bsum);
    k_scan3 <<<NB, SB, 0, stream>>>(locx, bsum, startA, cursor);
    k_build <<<(NE + 255) / 256, 256, 0, stream>>>(src, dst, cursor, csr);
    k_bounds<<<(NN + 255) / 256, 256, 0, stream>>>(batch, gs);
    k_embedT<<<(NN * 64 + 255) / 256, 256, 0, stream>>>(x, emb, T0);

    // ---- layer 1 ----
    k_agg2<<<((NN + 127) / 128) * 8, 256, 0, stream>>>(startA, csr, T0, TA);
    k_lin3<<<(NN + 255) / 256, 256, 0, stream>>>(TA, T0, W1l, b1l, W1r, T0);
    // ---- layer 2 ----
    k_agg2<<<((NN + 127) / 128) * 8, 256, 0, stream>>>(startA, csr, T0, TA);
    k_lin3<<<(NN + 255) / 256, 256, 0, stream>>>(TA, T0, W2l, b2l, W2r, TA);

    // ---- readout ----
    k_pools<<<(NN + 255) / 256, 256, 0, stream>>>(TA, batch, pooled);
    k_out<<<NG / 4, 256, 0, stream>>>(gs, pooled, Wout, bout, out);
}

// Round 11
// 440.135 us; speedup vs baseline: 1.6805x; 1.2204x over previous
//
#include <hip/hip_runtime.h>

#define NN 100000
#define NE 1200000
#define NG 2048
#define VOCAB 10000
#define D 64
#define C 2

#define NBK 196      // coarse buckets of 512 nodes (dst >> 9)
#define BSH 9
#define SLOT 7168    // per-bucket slot stride; mean 6144, sd 78 -> +13 sigma

__device__ __forceinline__ int atomAddI(int* p, int v) {
    return __hip_atomic_fetch_add(p, v, __ATOMIC_RELAXED, __HIP_MEMORY_SCOPE_AGENT);
}
__device__ __forceinline__ void atomAddF(float* p, float v) {
    __hip_atomic_fetch_add(p, v, __ATOMIC_RELAXED, __HIP_MEMORY_SCOPE_AGENT);
}

// ---------------- phase A: coarse bucket scatter (packed src|dlow) ----------------
__global__ void __launch_bounds__(256) k_bucket(const int* __restrict__ src,
        const int* __restrict__ dst, int* __restrict__ bcur, unsigned* __restrict__ barr) {
    __shared__ int hcnt[NBK], hbase[NBK], hrank[NBK];
    int tid = threadIdx.x;
    if (tid < NBK) { hcnt[tid] = 0; hrank[tid] = 0; }
    __syncthreads();
    int per = (NE + gridDim.x - 1) / gridDim.x;
    int e0 = blockIdx.x * per, e1 = min(e0 + per, NE);
    for (int e = e0 + tid; e < e1; e += 256)
        atomicAdd(&hcnt[dst[e] >> BSH], 1);
    __syncthreads();
    if (tid < NBK) {
        int c = hcnt[tid];
        hbase[tid] = c ? atomAddI(&bcur[tid], c) : 0;
    }
    __syncthreads();
    for (int e = e0 + tid; e < e1; e += 256) {
        int d = dst[e], s = src[e];
        int b = d >> BSH;
        int r = atomicAdd(&hrank[b], 1);
        barr[(size_t)b * SLOT + hbase[b] + r] = ((unsigned)s << BSH) | (unsigned)(d & 511);
    }
}

// ---------------- bucket-count scan ----------------
__global__ void __launch_bounds__(256) k_bscan(const int* __restrict__ bcur,
        int* __restrict__ bstart, int* __restrict__ start) {
    __shared__ int sm[256];
    int t = threadIdx.x;
    int v0 = (t < NBK) ? bcur[t] : 0;
    sm[t] = v0;
    __syncthreads();
    for (int off = 1; off < 256; off <<= 1) {
        int v = (t >= off) ? sm[t - off] : 0;
        __syncthreads();
        sm[t] += v;
        __syncthreads();
    }
    if (t < NBK) bstart[t] = sm[t] - v0;
    if (t == 0) { bstart[NBK] = NE; start[NN] = NE; }
}

// ---------------- phase B: exact CSR within each bucket ----------------
__global__ void __launch_bounds__(256) k_sortb(const int* __restrict__ bcur,
        const int* __restrict__ bstart, const unsigned* __restrict__ barr,
        int* __restrict__ start, int* __restrict__ csr) {
    __shared__ int cnt[512], loc[512], sm[256];
    int t = threadIdx.x;
    int b = blockIdx.x;
    cnt[t] = 0; cnt[t + 256] = 0;
    __syncthreads();
    int count = bcur[b];
    int base  = bstart[b];
    const unsigned* bp = barr + (size_t)b * SLOT;
    for (int i = t; i < count; i += 256)
        atomicAdd(&cnt[bp[i] & 511], 1);
    __syncthreads();
    int c0 = cnt[2 * t], c1 = cnt[2 * t + 1];
    int s = c0 + c1;
    sm[t] = s;
    __syncthreads();
    for (int off = 1; off < 256; off <<= 1) {
        int v = (t >= off) ? sm[t - off] : 0;
        __syncthreads();
        sm[t] += v;
        __syncthreads();
    }
    int ex = sm[t] - s;
    loc[2 * t] = ex; loc[2 * t + 1] = ex + c0;
    int g0 = b << BSH;
    if (g0 + 2 * t < NN)     start[g0 + 2 * t]     = base + ex;
    if (g0 + 2 * t + 1 < NN) start[g0 + 2 * t + 1] = base + ex + c0;
    __syncthreads();
    for (int i = t; i < count; i += 256) {
        unsigned p = bp[i];
        int r = atomicAdd(&loc[p & 511], 1);
        csr[base + r] = (int)(p >> BSH);
    }
}

// ---------------- embedding -> h0 slabs T0[c][n][8] ----------------
__global__ void __launch_bounds__(256) k_embedT(const int* __restrict__ x, const float* __restrict__ emb,
                         float* __restrict__ T0) {
    int tid = blockIdx.x * blockDim.x + threadIdx.x;
    if (tid >= NN * 64) return;
    int c = tid / (NN * 8);
    int r = tid % (NN * 8);
    int n = r >> 3, f = r & 7;
    T0[tid] = emb[(size_t)x[n] * 64 + c * 8 + f];
}

// ---------------- chunked aggregate: no-shfl layout, unroll 4 ----------------
__global__ void __launch_bounds__(256) k_agg2(const int* __restrict__ start,
        const int* __restrict__ csr, const float* __restrict__ gT,
        float* __restrict__ aggT) {
    int tid = threadIdx.x;
    int lane = tid & 63, wave = tid >> 6;
    int c  = blockIdx.x & 7;
    int nb = blockIdx.x >> 3;            // 0..781
    int f = lane & 7, nsub = lane >> 3;  // nsub 0..7
    const float* gsl = gT + (size_t)c * NN * 8;
    float* asl = aggT + (size_t)c * NN * 8;

    // streaming L2 warm of this block's slab slice
    float pf = 0.f;
    {
        int i = nb * 256 + tid;
        if (i < NN * 2) {
            float4 v = ((const float4*)gsl)[i];
            pf = v.x * 0.0f;
        }
    }

    int n0 = nb * 128;
    for (int b = 0; b < 4; ++b) {
        int n = n0 + wave * 32 + b * 8 + nsub;
        if (n >= NN) break;
        int s0 = start[n], s1 = start[n + 1];
        float inv = 1.0f / (float)max(s1 - s0, 1);
        float acc = pf, acc2 = 0.f;
        int i = s0;
        for (; i + 4 <= s1; i += 4) {
            int c0 = csr[i], c1 = csr[i + 1], c2 = csr[i + 2], c3 = csr[i + 3];
            float v0 = gsl[(size_t)c0 * 8 + f];
            float v1 = gsl[(size_t)c1 * 8 + f];
            float v2 = gsl[(size_t)c2 * 8 + f];
            float v3 = gsl[(size_t)c3 * 8 + f];
            acc += v0 + v1;
            acc2 += v2 + v3;
        }
        for (; i < s1; ++i) acc += gsl[(size_t)csr[i] * 8 + f];
        asl[(size_t)n * 8 + f] = (acc + acc2) * inv;
    }
}

// ---------------- SAGE linear (+ReLU): one THREAD per node ----------------
__global__ void __launch_bounds__(256) k_lin3(const float* __restrict__ aggT,
        const float* __restrict__ rootT,
        const float* __restrict__ Wl, const float* __restrict__ bl,
        const float* __restrict__ Wr, float* __restrict__ outT) {
    int tid = blockIdx.x * 256 + threadIdx.x;
    int n = tid < NN ? tid : NN - 1;   // clamp; store guarded

    float acc[64];
#pragma unroll
    for (int d = 0; d < 64; ++d) acc[d] = bl[d];

    const float4* ap = (const float4*)(aggT + (size_t)n * 8);
    const float4* rp = (const float4*)(rootT + (size_t)n * 8);
    const size_t cstep = (size_t)NN * 2;   // chunk stride in float4s

    float4 a0 = ap[0], a1 = ap[1], r0 = rp[0], r1 = rp[1];
    for (int c = 0; c < 8; ++c) {
        float av[8] = {a0.x, a0.y, a0.z, a0.w, a1.x, a1.y, a1.z, a1.w};
        float rv[8] = {r0.x, r0.y, r0.z, r0.w, r1.x, r1.y, r1.z, r1.w};
        if (c < 7) {
            size_t off = (size_t)(c + 1) * cstep;
            a0 = ap[off]; a1 = ap[off + 1];
            r0 = rp[off]; r1 = rp[off + 1];
        }
        const float* wlc = Wl + c * 8;   // row d, cols c*8..c*8+7
        const float* wrc = Wr + c * 8;
#pragma unroll
        for (int d = 0; d < 64; ++d) {
#pragma unroll
            for (int k = 0; k < 8; ++k) {
                acc[d] += av[k] * wlc[d * 64 + k];
                acc[d] += rv[k] * wrc[d * 64 + k];
            }
        }
    }

    if (tid < NN) {
#pragma unroll
        for (int c = 0; c < 8; ++c) {
            float4 o0, o1;
            o0.x = fmaxf(acc[c * 8 + 0], 0.f); o0.y = fmaxf(acc[c * 8 + 1], 0.f);
            o0.z = fmaxf(acc[c * 8 + 2], 0.f); o0.w = fmaxf(acc[c * 8 + 3], 0.f);
            o1.x = fmaxf(acc[c * 8 + 4], 0.f); o1.y = fmaxf(acc[c * 8 + 5], 0.f);
            o1.z = fmaxf(acc[c * 8 + 6], 0.f); o1.w = fmaxf(acc[c * 8 + 7], 0.f);
            float4* op = (float4*)(outT + (size_t)c * NN * 8 + (size_t)n * 8);
            op[0] = o0; op[1] = o1;
        }
    }
}

// ---------------- per-graph mean-pool from h2 slabs (batch sorted) ----------------
__global__ void __launch_bounds__(256) k_pools(const float* __restrict__ hT,
        const int* __restrict__ batch, float* __restrict__ pooled) {
    int lane = threadIdx.x & 63;
    int wave = threadIdx.x >> 6;
    int n0 = blockIdx.x * 256 + wave * 64;
    if (n0 >= NN) return;
    const float* base = hT + (size_t)(lane >> 3) * NN * 8 + (lane & 7);
    int gcur = batch[n0];
    float rsum = 0.f;
    int nend = min(n0 + 64, NN);
    for (int n = n0; n < nend; ++n) {
        float v = base[(size_t)n * 8];
        int g = batch[n];
        if (g != gcur) {
            atomAddF(&pooled[(size_t)gcur * D + lane], rsum);
            rsum = 0.f; gcur = g;
        }
        rsum += v;
    }
    atomAddF(&pooled[(size_t)gcur * D + lane], rsum);
}

// ---------------- readout ----------------
__global__ void __launch_bounds__(256) k_bounds(const int* __restrict__ batch, int* __restrict__ gs) {
    int n = blockIdx.x * blockDim.x + threadIdx.x;
    if (n >= NN) return;
    int b = batch[n];
    if (n == 0) {
        for (int g = 0; g <= b; ++g) gs[g] = 0;
    } else {
        int bp = batch[n - 1];
        for (int g = bp + 1; g <= b; ++g) gs[g] = n;
    }
    if (n == NN - 1) {
        for (int g = b + 1; g <= NG; ++g) gs[g] = NN;
    }
}

__global__ void __launch_bounds__(256) k_out(const int* __restrict__ gs,
        const float* __restrict__ pooled, const float* __restrict__ Wout,
        const float* __restrict__ bout, float* __restrict__ out) {
    int lane = threadIdx.x & 63;
    int wave = threadIdx.x >> 6;
    int g = blockIdx.x * 4 + wave;       // 512 blocks
    int s0 = gs[g], s1 = gs[g + 1];
    float p = pooled[(size_t)g * D + lane] / (float)max(s1 - s0, 1);
    float c0 = p * Wout[lane];
    float c1 = p * Wout[D + lane];
#pragma unroll
    for (int off = 32; off > 0; off >>= 1) {
        c0 += __shfl_down(c0, off, 64);
        c1 += __shfl_down(c1, off, 64);
    }
    if (lane == 0) {
        out[g * C + 0] = c0 + bout[0];
        out[g * C + 1] = c1 + bout[1];
    }
}

extern "C" void kernel_launch(void* const* d_in, const int* in_sizes, int n_in,
                              void* d_out, int out_size, void* d_ws, size_t ws_size,
                              hipStream_t stream) {
    const int*   x     = (const int*)d_in[0];
    const int*   src   = (const int*)d_in[1];
    const int*   dst   = src + NE;
    const int*   batch = (const int*)d_in[2];
    const float* emb   = (const float*)d_in[3];
    const float* W1l   = (const float*)d_in[4];
    const float* b1l   = (const float*)d_in[5];
    const float* W1r   = (const float*)d_in[6];
    const float* W2l   = (const float*)d_in[7];
    const float* b2l   = (const float*)d_in[8];
    const float* W2r   = (const float*)d_in[9];
    const float* Wout  = (const float*)d_in[10];
    const float* bout  = (const float*)d_in[11];
    float* out = (float*)d_out;

    float* T0     = (float*)d_ws;                 // NN*64  h0 -> h1 slabs (in place)
    float* TA     = T0 + (size_t)NN * 64;         // NN*64  agg slabs -> h2 slabs (in place)
    float* pooled = TA + (size_t)NN * 64;         // NG*64
    int* bcur   = (int*)(pooled + (size_t)NG * 64);  // NBK  (contiguous w/ pooled for memset)
    int* bstart = bcur + NBK;                        // NBK+1
    int* startA = bstart + NBK + 1;                  // NN+1
    int* gs     = startA + NN + 1;                   // NG+1
    int* csr    = gs + NG + 1;                       // NE
    unsigned* barr = (unsigned*)(csr + NE);          // NBK*SLOT (~5.6 MB)

    hipMemsetAsync(pooled, 0, ((size_t)NG * 64 + NBK) * sizeof(float), stream);

    k_bucket<<<192, 256, 0, stream>>>(src, dst, bcur, barr);
    k_bscan <<<1, 256, 0, stream>>>(bcur, bstart, startA);
    k_sortb <<<NBK, 256, 0, stream>>>(bcur, bstart, barr, startA, csr);
    k_bounds<<<(NN + 255) / 256, 256, 0, stream>>>(batch, gs);
    k_embedT<<<(NN * 64 + 255) / 256, 256, 0, stream>>>(x, emb, T0);

    // ---- layer 1 ----
    k_agg2<<<((NN + 127) / 128) * 8, 256, 0, stream>>>(startA, csr, T0, TA);
    k_lin3<<<(NN + 255) / 256, 256, 0, stream>>>(TA, T0, W1l, b1l, W1r, T0);
    // ---- layer 2 ----
    k_agg2<<<((NN + 127) / 128) * 8, 256, 0, stream>>>(startA, csr, T0, TA);
    k_lin3<<<(NN + 255) / 256, 256, 0, stream>>>(TA, T0, W2l, b2l, W2r, TA);

    // ---- readout ----
    k_pools<<<(NN + 255) / 256, 256, 0, stream>>>(TA, batch, pooled);
    k_out<<<NG / 4, 256, 0, stream>>>(gs, pooled, Wout, bout, out);
}